// Round 6
// baseline (148.020 us; speedup 1.0000x reference)
//
#include <hip/hip_runtime.h>
#include <hip/hip_bf16.h>

#define NBATCH 8
#define BROWS 256
#define KDIM 512
#define HIDD 512
#define GDIM 2048

// packed tile geometry: per (nb,cb,phase): [mat(4)][n(64)][k(72 bf16, 64 data + 8 pad)]
#define ROWB 144              // 72 * 2B
#define MATSZ (64 * ROWB)     // 9216
#define PCHUNK (4 * MATSZ)    // 36864 bytes per phase tile
#define NPH 8                 // 512 / 64

// ws layout
#define WS_XQH 256
#define WS_HXH (256 + 2097152)
#define WS_HXL (256 + 2 * 2097152)
#define WS_BIAS (256 + 3 * 2097152)
#define WS_P (256 + 3 * 2097152 + 65536)

typedef float f32x4 __attribute__((ext_vector_type(4)));
typedef float f32x16 __attribute__((ext_vector_type(16)));
typedef __bf16 bf16x8 __attribute__((ext_vector_type(8)));
typedef unsigned int u32;

__device__ __forceinline__ void gload16(const void* g, void* l) {
    __builtin_amdgcn_global_load_lds((const __attribute__((address_space(1))) u32*)g,
                                     (__attribute__((address_space(3))) u32*)l, 16, 0, 0);
}

__device__ __forceinline__ unsigned fenc(float f) {
    unsigned u = __float_as_uint(f);
    return (u & 0x80000000u) ? ~u : (u | 0x80000000u);
}
__device__ __forceinline__ float fdec(unsigned e) {
    unsigned u = (e & 0x80000000u) ? (e & 0x7fffffffu) : ~e;
    return __uint_as_float(u);
}
__device__ __forceinline__ unsigned umaxu(unsigned a, unsigned b) { return a > b ? a : b; }

__device__ __forceinline__ float qpact(float x, float a) {
    float ax = fabsf(x);
    float p  = copysignf(0.5f * (ax - fabsf(ax - a) + a), x);
    float x01 = p / a;
    x01 = fminf(fmaxf(x01, -0.9921875f), 0.9921875f);
    return (rintf(x01 * 128.f) * 0.0078125f) * a;
}
__device__ __forceinline__ float q1(float x) {
    float x01 = fminf(fmaxf(x, -0.9921875f), 0.9921875f);
    return rintf(x01 * 128.f) * 0.0078125f;
}
__device__ __forceinline__ float sigmf(float x) { return 1.0f / (1.0f + expf(-x)); }

// y=0..3: global maxes of w_ih, w_hh, b_ih, b_hh.  y=4: A-side prep.
__global__ void k_maxprep(const float* __restrict__ w_ih, const float* __restrict__ w_hh,
                          const float* __restrict__ b_ih, const float* __restrict__ b_hh,
                          const float* __restrict__ input, const float* __restrict__ hx,
                          const float* __restrict__ a1,
                          unsigned* __restrict__ maxes,
                          __hip_bfloat16* __restrict__ xqh, __hip_bfloat16* __restrict__ hxh,
                          __hip_bfloat16* __restrict__ hxl) {
    int y = blockIdx.y;
    int stride = gridDim.x * blockDim.x;
    int gtid = blockIdx.x * blockDim.x + threadIdx.x;
    if (y < 4) {
        const float* src = y == 0 ? w_ih : y == 1 ? w_hh : y == 2 ? b_ih : b_hh;
        int n4 = (y < 2 ? NBATCH * KDIM * GDIM : NBATCH * GDIM) >> 2;
        unsigned best = 0u;
        for (int i = gtid; i < n4; i += stride) {
            float4 v = ((const float4*)src)[i];
            best = umaxu(best, fenc(v.x)); best = umaxu(best, fenc(v.y));
            best = umaxu(best, fenc(v.z)); best = umaxu(best, fenc(v.w));
        }
        #pragma unroll
        for (int off = 32; off > 0; off >>= 1)
            best = umaxu(best, (unsigned)__shfl_down((int)best, off, 64));
        __shared__ unsigned red[4];
        int lane = threadIdx.x & 63, wv = threadIdx.x >> 6;
        if (lane == 0) red[wv] = best;
        __syncthreads();
        if (threadIdx.x == 0) {
            unsigned b2 = umaxu(umaxu(red[0], red[1]), umaxu(red[2], red[3]));
            atomicMax(&maxes[y], b2);
        }
    } else {
        const int NX = NBATCH * BROWS * KDIM;
        const int NH = NBATCH * BROWS * HIDD;
        int total = NX + NH;
        for (int i = gtid; i < total; i += stride) {
            if (i < NX) {
                int nb = i >> 17;
                int rem = i & 131071;
                float v = qpact(input[rem], a1[nb]);
                xqh[i] = __float2bfloat16(v);
            } else {
                int j = i - NX;
                float h = hx[j];
                __hip_bfloat16 hi = __float2bfloat16(h);
                hxh[j] = hi;
                hxl[j] = __float2bfloat16(h - __bfloat162float(hi));
            }
        }
    }
}

// blocks 0..255: pack e = wq + 0.05*max*z into GEMM LDS-image layout.
// block 256: bias_comb.
__global__ __launch_bounds__(1024) void k_pack(
    const float* __restrict__ w_ih, const float* __restrict__ w_hh,
    const float* __restrict__ n_ih, const float* __restrict__ n_hh,
    const float* __restrict__ b_ih, const float* __restrict__ b_hh,
    const float* __restrict__ nbih, const float* __restrict__ nbhh,
    const unsigned* __restrict__ maxes,
    char* __restrict__ P, float* __restrict__ bias_comb) {
    int bid = blockIdx.x;
    if (bid == 256) {
        float mb_ih = fdec(maxes[2]);
        float mb_hh = fdec(maxes[3]);
        #pragma unroll
        for (int it = 0; it < 16; ++it) {
            int j = it * 1024 + threadIdx.x;
            bias_comb[j] = q1(b_ih[j]) + (nbih[j] * mb_ih) * 0.05f
                         + q1(b_hh[j]) + (nbhh[j] * mb_hh) * 0.05f;
        }
        return;
    }
    int nb = bid >> 5;
    int p  = (bid >> 1) & 15;      // 16 k-slices of 32
    int ch = bid & 1;              // col half
    int k0 = p * 32;
    int ph = p >> 1;
    int half = p & 1;
    float c_ih = fdec(maxes[0]);
    float c_hh = fdec(maxes[1]);

    int c = ch * 1024 + threadIdx.x;       // global G-col, reads contiguous per wave
    int g  = c >> 9;                        // gate 0..3 (i,j,f,o)
    int cw = c & 511;
    int cb = cw >> 4;
    int cc = cw & 15;
    int n  = (g << 4) + cc;                 // slot in [0,64)

    char* rowP = P + ((size_t)((nb * 32 + cb) * 8 + ph)) * PCHUNK + n * ROWB + half * 64;
    size_t boff = (size_t)nb * KDIM * GDIM;

    #pragma unroll
    for (int pair = 0; pair < 2; ++pair) {
        const float* W = (pair ? w_hh : w_ih) + boff;
        const float* Z = (pair ? n_hh : n_ih) + boff;
        float cm = pair ? c_hh : c_ih;
        char* dhi = rowP + (pair * 2) * MATSZ;
        char* dlo = rowP + (pair * 2 + 1) * MATSZ;
        #pragma unroll
        for (int c4 = 0; c4 < 4; ++c4) {
            bf16x8 hi8, lo8;
            #pragma unroll
            for (int j = 0; j < 8; ++j) {
                int k = k0 + c4 * 8 + j;
                float w = W[(size_t)k * GDIM + c];
                float z = Z[(size_t)k * GDIM + c];
                float wq = rintf(fminf(fmaxf(w, -0.9921875f), 0.9921875f) * 128.f) * 0.0078125f;
                float e = wq + (z * cm) * 0.05f;
                __hip_bfloat16 h = __float2bfloat16(e);
                float lof = e - __bfloat162float(h);
                __hip_bfloat16 lb = __float2bfloat16(lof);
                hi8[j] = *reinterpret_cast<__bf16*>(&h);
                lo8[j] = *reinterpret_cast<__bf16*>(&lb);
            }
            *(bf16x8*)(dhi + c4 * 16) = hi8;
            *(bf16x8*)(dlo + c4 * 16) = lo8;
        }
    }
}

// 8 waves: mband = w&3 (64 rows), cg = w>>2 (32 gate-slots). m-rep 2, 32x32x16.
__global__ __launch_bounds__(512, 2) void k_gemm(
    const char* __restrict__ P,
    const __hip_bfloat16* __restrict__ xqh, const __hip_bfloat16* __restrict__ hxh,
    const __hip_bfloat16* __restrict__ hxl,
    const float* __restrict__ bias_comb, const float* __restrict__ cx,
    const float* __restrict__ a3, const float* __restrict__ a4, const float* __restrict__ a5,
    const float* __restrict__ a6, const float* __restrict__ a7, const float* __restrict__ a8,
    const float* __restrict__ a9, const float* __restrict__ a10, const float* __restrict__ a11,
    float* __restrict__ out_h, float* __restrict__ out_c)
{
    __shared__ __align__(16) char Tl[2][PCHUNK];   // 72 KB double-buffered B tiles
    __shared__ float Gx[4][256][16];               // 64 KB gate exchange

    int tid = threadIdx.x;
    int lane = tid & 63, w = tid >> 6;
    int l31 = lane & 31, l5 = lane >> 5;
    int nb = blockIdx.x & 7;
    int cb = blockIdx.x >> 3;
    int mband = w & 3;
    int cg = w >> 2;

    const char* Pblk = P + (size_t)(nb * 32 + cb) * 8 * PCHUNK;
    const __hip_bfloat16* xq_b = xqh + nb * BROWS * KDIM;
    const __hip_bfloat16* hh_b = hxh + nb * BROWS * KDIM;
    const __hip_bfloat16* hl_b = hxl + nb * BROWS * KDIM;

    f32x16 acc0 = {}, acc1 = {};
    int row0 = mband * 64 + l31;

#define STAGE(BUF, PH) {                                                     \
    const char* src = Pblk + (size_t)(PH) * PCHUNK;                          \
    _Pragma("unroll")                                                        \
    for (int t = 0; t < 5; ++t) {                                            \
        if (t * 8 + w < 36) {                                                \
            int off = t * 8192 + w * 1024;                                   \
            gload16(src + off + lane * 16, &Tl[BUF][off]);                   \
        }                                                                    \
    } }

#define MFMA(ACC, A, B) ACC = __builtin_amdgcn_mfma_f32_32x32x16_bf16(A, B, ACC, 0, 0, 0)

    STAGE(0, 0);
    __syncthreads();
    int cur = 0;

    for (int ph = 0; ph < NPH; ++ph) {
        // A fragments for this phase (global, L2/L3-hot)
        bf16x8 ax[2][4], ah[2][4], al[2][4];
        #pragma unroll
        for (int kc = 0; kc < 4; ++kc) {
            int k = ph * 64 + kc * 16 + l5 * 8;
            #pragma unroll
            for (int mi = 0; mi < 2; ++mi) {
                int r = row0 + mi * 32;
                ax[mi][kc] = *(const bf16x8*)(xq_b + r * KDIM + k);
                ah[mi][kc] = *(const bf16x8*)(hh_b + r * KDIM + k);
                al[mi][kc] = *(const bf16x8*)(hl_b + r * KDIM + k);
            }
        }
        // prefetch next tile direct-to-LDS (stays in flight through compute)
        if (ph + 1 < NPH) STAGE(cur ^ 1, ph + 1);

        const char* Tb = Tl[cur];
        int nrow = cg * 32 + l31;
        #pragma unroll
        for (int kc = 0; kc < 4; ++kc) {
            int bo = nrow * ROWB + kc * 32 + l5 * 16;
            bf16x8 b0 = *(const bf16x8*)(Tb + 0 * MATSZ + bo);
            bf16x8 b1 = *(const bf16x8*)(Tb + 1 * MATSZ + bo);
            bf16x8 b2 = *(const bf16x8*)(Tb + 2 * MATSZ + bo);
            bf16x8 b3 = *(const bf16x8*)(Tb + 3 * MATSZ + bo);
            MFMA(acc0, ax[0][kc], b0); MFMA(acc0, ax[0][kc], b1);
            MFMA(acc0, ah[0][kc], b2); MFMA(acc0, ah[0][kc], b3);
            MFMA(acc0, al[0][kc], b2);
            MFMA(acc1, ax[1][kc], b0); MFMA(acc1, ax[1][kc], b1);
            MFMA(acc1, ah[1][kc], b2); MFMA(acc1, ah[1][kc], b3);
            MFMA(acc1, al[1][kc], b2);
        }
        __syncthreads();
        cur ^= 1;
    }

    // gate exchange through LDS: Gx[gate][row][hcol16]
    int gq = (cg * 32 + l31) >> 4;
    int hq = l31 & 15;
    #pragma unroll
    for (int r = 0; r < 16; ++r) {
        int rw = mband * 64 + (r & 3) + 8 * (r >> 2) + 4 * l5;
        Gx[gq][rw][hq] = acc0[r];
        Gx[gq][rw + 32][hq] = acc1[r];
    }
    __syncthreads();

    int h = tid & 15;
    int hcol = cb * 16 + h;
    float A3 = a3[nb], A4 = a4[nb], A5 = a5[nb], A6 = a6[nb], A7 = a7[nb];
    float A8 = a8[nb], A9 = a9[nb], A10 = a10[nb], A11 = a11[nb];
    float bc_i = bias_comb[nb * GDIM + hcol];
    float bc_j = bias_comb[nb * GDIM + 512 + hcol];
    float bc_f = bias_comb[nb * GDIM + 1024 + hcol];
    float bc_o = bias_comb[nb * GDIM + 1536 + hcol];
    #pragma unroll
    for (int s = 0; s < 8; ++s) {
        int row = s * 32 + (tid >> 4);
        float gi = Gx[0][row][h] + bc_i;
        float gj = Gx[1][row][h] + bc_j;
        float gf = Gx[2][row][h] + bc_f;
        float go = Gx[3][row][h] + bc_o;
        float fg = qpact(sigmf(gf), A3);
        float ig = qpact(sigmf(gi), A4);
        float act = qpact(tanhf(gj), A5);
        float og = qpact(sigmf(go), A6);
        int oidx = (nb * BROWS + row) * HIDD + hcol;
        float cv = cx[oidx];
        float gated = qpact(cv * fg, A7);
        float actin = qpact(ig * act, A8);
        float ncv = qpact(gated + actin, A9);
        float acv = qpact(tanhf(ncv), A10);
        float nhv = qpact(acv * og, A11);
        out_h[oidx] = nhv;
        out_c[oidx] = ncv;
    }
}

extern "C" void kernel_launch(void* const* d_in, const int* in_sizes, int n_in,
                              void* d_out, int out_size, void* d_ws, size_t ws_size,
                              hipStream_t stream) {
    const float* input = (const float*)d_in[0];
    const float* hx    = (const float*)d_in[1];
    const float* cx    = (const float*)d_in[2];
    const float* w_ih  = (const float*)d_in[3];
    const float* w_hh  = (const float*)d_in[4];
    const float* b_ih  = (const float*)d_in[5];
    const float* b_hh  = (const float*)d_in[6];
    const float* n_wih = (const float*)d_in[7];
    const float* n_whh = (const float*)d_in[8];
    const float* n_bih = (const float*)d_in[9];
    const float* n_bhh = (const float*)d_in[10];
    const float* a1  = (const float*)d_in[11];
    const float* a3  = (const float*)d_in[12];
    const float* a4  = (const float*)d_in[13];
    const float* a5  = (const float*)d_in[14];
    const float* a6  = (const float*)d_in[15];
    const float* a7  = (const float*)d_in[16];
    const float* a8  = (const float*)d_in[17];
    const float* a9  = (const float*)d_in[18];
    const float* a10 = (const float*)d_in[19];
    const float* a11 = (const float*)d_in[20];

    float* out_h = (float*)d_out;
    float* out_c = out_h + NBATCH * BROWS * HIDD;

    char* ws = (char*)d_ws;
    unsigned* maxes = (unsigned*)ws;
    __hip_bfloat16* xqh = (__hip_bfloat16*)(ws + WS_XQH);
    __hip_bfloat16* hxh = (__hip_bfloat16*)(ws + WS_HXH);
    __hip_bfloat16* hxl = (__hip_bfloat16*)(ws + WS_HXL);
    float* bias_comb    = (float*)(ws + WS_BIAS);
    char* P             = ws + WS_P;

    hipMemsetAsync(maxes, 0, 16, stream);
    k_maxprep<<<dim3(256, 5), 256, 0, stream>>>(w_ih, w_hh, b_ih, b_hh, input, hx, a1,
                                                maxes, xqh, hxh, hxl);
    k_pack<<<257, 1024, 0, stream>>>(w_ih, w_hh, n_wih, n_whh, b_ih, b_hh, n_bih, n_bhh,
                                     maxes, P, bias_comb);
    k_gemm<<<NBATCH * 32, 512, 0, stream>>>(P, xqh, hxh, hxl, bias_comb, cx,
                                            a3, a4, a5, a6, a7, a8, a9, a10, a11,
                                            out_h, out_c);
}

// Round 7
// 95.082 us; speedup vs baseline: 1.5568x; 1.5568x over previous
//
#include <hip/hip_runtime.h>
#include <hip/hip_bf16.h>

#define NBATCH 8
#define BROWS 256
#define KDIM 512
#define HIDD 512
#define GDIM 2048
#define KSTEP 64
#define NIT (KDIM / KSTEP)

typedef float f32x4 __attribute__((ext_vector_type(4)));
typedef __bf16 bf16x8 __attribute__((ext_vector_type(8)));

__device__ __forceinline__ unsigned fenc(float f) {
    unsigned u = __float_as_uint(f);
    return (u & 0x80000000u) ? ~u : (u | 0x80000000u);
}
__device__ __forceinline__ float fdec(unsigned e) {
    unsigned u = (e & 0x80000000u) ? (e & 0x7fffffffu) : ~e;
    return __uint_as_float(u);
}
__device__ __forceinline__ unsigned umaxu(unsigned a, unsigned b) { return a > b ? a : b; }

// quant(pact(x,a), 8, a)  -- all a's are powers of 2 so /a, *a are exact
__device__ __forceinline__ float qpact(float x, float a) {
    float ax = fabsf(x);
    float p  = copysignf(0.5f * (ax - fabsf(ax - a) + a), x);
    float x01 = p / a;
    x01 = fminf(fmaxf(x01, -0.9921875f), 0.9921875f);
    return (rintf(x01 * 128.f) * 0.0078125f) * a;
}
// quant(x, 8, 1.0)
__device__ __forceinline__ float q1(float x) {
    float x01 = fminf(fmaxf(x, -0.9921875f), 0.9921875f);
    return rintf(x01 * 128.f) * 0.0078125f;
}
__device__ __forceinline__ float sigmf(float x) { return 1.0f / (1.0f + expf(-x)); }

// y = 0..5: stream-reduce max over w_ih, w_hh, b_ih, b_hh, n_wih, n_whh.
// The n_* maxes are unused downstream; their purpose is warming L3 so
// k_gemm's noise reads hit cache instead of cold 64B-granule HBM.
__global__ void k_max(const float* __restrict__ w_ih, const float* __restrict__ w_hh,
                      const float* __restrict__ b_ih, const float* __restrict__ b_hh,
                      const float* __restrict__ n_ih, const float* __restrict__ n_hh,
                      unsigned* __restrict__ omax) {
    int which = blockIdx.y;
    const float* src = which == 0 ? w_ih : which == 1 ? w_hh : which == 2 ? b_ih :
                       which == 3 ? b_hh : which == 4 ? n_ih : n_hh;
    int n4 = ((which == 2 || which == 3) ? NBATCH * GDIM : NBATCH * KDIM * GDIM) >> 2;
    unsigned best = 0u;
    int stride = gridDim.x * blockDim.x;
    for (int i = blockIdx.x * blockDim.x + threadIdx.x; i < n4; i += stride) {
        float4 v = ((const float4*)src)[i];
        best = umaxu(best, fenc(v.x)); best = umaxu(best, fenc(v.y));
        best = umaxu(best, fenc(v.z)); best = umaxu(best, fenc(v.w));
    }
    #pragma unroll
    for (int off = 32; off > 0; off >>= 1)
        best = umaxu(best, (unsigned)__shfl_down((int)best, off, 64));
    __shared__ unsigned red[4];
    int lane = threadIdx.x & 63, wv = threadIdx.x >> 6;
    if (lane == 0) red[wv] = best;
    __syncthreads();
    if (threadIdx.x == 0) {
        unsigned b2 = umaxu(umaxu(red[0], red[1]), umaxu(red[2], red[3]));
        atomicMax(&omax[which], b2);
    }
}

__global__ void k_prep(const float* __restrict__ input, const float* __restrict__ hx,
                       const float* __restrict__ bih, const float* __restrict__ bhh,
                       const float* __restrict__ nbih, const float* __restrict__ nbhh,
                       const float* __restrict__ a1, const unsigned* __restrict__ maxes,
                       __hip_bfloat16* __restrict__ xqh, __hip_bfloat16* __restrict__ hxh,
                       __hip_bfloat16* __restrict__ hxl, float* __restrict__ bias_comb) {
    const int NX = NBATCH * BROWS * KDIM;
    const int NH = NBATCH * BROWS * HIDD;
    const int NBC = NBATCH * GDIM;
    int total = NX + NH + NBC;
    int stride = gridDim.x * blockDim.x;
    for (int i = blockIdx.x * blockDim.x + threadIdx.x; i < total; i += stride) {
        if (i < NX) {
            int nb = i >> 17;              // /(256*512)
            int rem = i & 131071;
            float v = qpact(input[rem], a1[nb]);
            xqh[i] = __float2bfloat16(v);  // exact: integers <=127 for a1=128
        } else if (i < NX + NH) {
            int j = i - NX;
            float h = hx[j];
            __hip_bfloat16 hi = __float2bfloat16(h);
            hxh[j] = hi;
            hxl[j] = __float2bfloat16(h - __bfloat162float(hi));
        } else {
            int j = i - NX - NH;
            float mb_ih = fdec(maxes[2]);
            float mb_hh = fdec(maxes[3]);
            bias_comb[j] = q1(bih[j]) + (nbih[j] * mb_ih) * 0.05f
                         + q1(bhh[j]) + (nbhh[j] * mb_hh) * 0.05f;
        }
    }
}

__global__ __launch_bounds__(1024, 1) void k_gemm(
    const float* __restrict__ w_ih, const float* __restrict__ w_hh,
    const float* __restrict__ n_ih, const float* __restrict__ n_hh,
    const __hip_bfloat16* __restrict__ xqh, const __hip_bfloat16* __restrict__ hxh,
    const __hip_bfloat16* __restrict__ hxl,
    const float* __restrict__ bias_comb, const float* __restrict__ cx,
    const float* __restrict__ a3, const float* __restrict__ a4, const float* __restrict__ a5,
    const float* __restrict__ a6, const float* __restrict__ a7, const float* __restrict__ a8,
    const float* __restrict__ a9, const float* __restrict__ a10, const float* __restrict__ a11,
    const unsigned* __restrict__ maxes,
    float* __restrict__ out_h, float* __restrict__ out_c)
{
    // double-buffered B tiles: [buf][mat][n=64][k=64 pad 72] bf16 -> 72 KB
    __shared__ __hip_bfloat16 Bsm[2][4][64][72];

    int tid = threadIdx.x;
    int lane = tid & 63, wv = tid >> 6;          // 16 waves
    int nb = blockIdx.x & 7;                     // batch -> XCD round-robin
    int cb = blockIdx.x >> 3;                    // 32 column-blocks of 16 HID cols

    const float* wih_b = w_ih + nb * KDIM * GDIM;
    const float* whh_b = w_hh + nb * KDIM * GDIM;
    const float* nih_b = n_ih + nb * KDIM * GDIM;
    const float* nhh_b = n_hh + nb * KDIM * GDIM;
    const __hip_bfloat16* xq_b = xqh + nb * BROWS * KDIM;
    const __hip_bfloat16* hh_b = hxh + nb * BROWS * KDIM;
    const __hip_bfloat16* hl_b = hxl + nb * BROWS * KDIM;

    float c_ih = fdec(maxes[0]);
    float c_hh = fdec(maxes[1]);

    f32x4 acc[4] = {};                           // one 16-row m-frag x 4 gate-frags

    int lh = lane & 15;
    int g  = lane >> 4;                          // 0..3
    int arow = (wv << 4) + lh;                   // this wave's 16 rows

    // staging map: thread -> one col n (0..63), one k-octet, one matrix pair
    int sn   = tid & 63;
    int soct = (tid >> 6) & 7;
    int shh  = tid >> 9;                         // 0: ih pair, 1: hh pair (wave-uniform)
    const float* wsrc = shh ? whh_b : wih_b;
    const float* zsrc = shh ? nhh_b : nih_b;
    float cmax = shh ? c_hh : c_ih;
    int matHi = shh << 1;                        // 0 or 2
    int scol = ((sn >> 4) << 9) + (cb << 4) + (sn & 15);

    float rwa[8], rza[8], rwb[8], rzb[8];
    bf16x8 ax0, ax1, ah0, ah1, al0, al1;

#define STAGE(RW, RZ, K0) {                                  \
    int kb = (K0) + (soct << 3);                             \
    _Pragma("unroll")                                        \
    for (int j = 0; j < 8; ++j) {                            \
        int gx = (kb + j) * GDIM + scol;                     \
        RW[j] = wsrc[gx]; RZ[j] = zsrc[gx];                  \
    } }

#define ALOAD(K0) {                                          \
    int a0 = arow * KDIM + (K0) + (g << 3);                  \
    ax0 = *(const bf16x8*)(xq_b + a0);                       \
    ax1 = *(const bf16x8*)(xq_b + a0 + 32);                  \
    ah0 = *(const bf16x8*)(hh_b + a0);                       \
    ah1 = *(const bf16x8*)(hh_b + a0 + 32);                  \
    al0 = *(const bf16x8*)(hl_b + a0);                       \
    al1 = *(const bf16x8*)(hl_b + a0 + 32);                  \
    }

#define CVT(P, RW, RZ) {                                     \
    bf16x8 hi8, lo8;                                         \
    _Pragma("unroll")                                        \
    for (int j = 0; j < 8; ++j) {                            \
        float w = RW[j];                                     \
        float wq = rintf(fminf(fmaxf(w, -0.9921875f), 0.9921875f) * 128.f) * 0.0078125f; \
        float e = wq + (RZ[j] * cmax) * 0.05f;               \
        __hip_bfloat16 h = __float2bfloat16(e);              \
        float lo = e - __bfloat162float(h);                  \
        __hip_bfloat16 l = __float2bfloat16(lo);             \
        hi8[j] = *reinterpret_cast<__bf16*>(&h);             \
        lo8[j] = *reinterpret_cast<__bf16*>(&l);             \
    }                                                        \
    *(bf16x8*)&Bsm[P][matHi][sn][soct << 3] = hi8;           \
    *(bf16x8*)&Bsm[P][matHi + 1][sn][soct << 3] = lo8; }

#define COMPUTE(P) {                                         \
    _Pragma("unroll")                                        \
    for (int nf = 0; nf < 4; ++nf) {                         \
        int n = (nf << 4) + lh;                              \
        int kb0 = g << 3, kb1 = 32 + kb0;                    \
        bf16x8 b0 = *(const bf16x8*)&Bsm[P][0][n][kb0];      \
        bf16x8 b1 = *(const bf16x8*)&Bsm[P][1][n][kb0];      \
        bf16x8 b2 = *(const bf16x8*)&Bsm[P][2][n][kb0];      \
        bf16x8 b3 = *(const bf16x8*)&Bsm[P][3][n][kb0];      \
        acc[nf] = __builtin_amdgcn_mfma_f32_16x16x32_bf16(ax0, b0, acc[nf], 0, 0, 0); \
        acc[nf] = __builtin_amdgcn_mfma_f32_16x16x32_bf16(ax0, b1, acc[nf], 0, 0, 0); \
        acc[nf] = __builtin_amdgcn_mfma_f32_16x16x32_bf16(ah0, b2, acc[nf], 0, 0, 0); \
        acc[nf] = __builtin_amdgcn_mfma_f32_16x16x32_bf16(ah0, b3, acc[nf], 0, 0, 0); \
        acc[nf] = __builtin_amdgcn_mfma_f32_16x16x32_bf16(al0, b2, acc[nf], 0, 0, 0); \
        b0 = *(const bf16x8*)&Bsm[P][0][n][kb1];             \
        b1 = *(const bf16x8*)&Bsm[P][1][n][kb1];             \
        b2 = *(const bf16x8*)&Bsm[P][2][n][kb1];             \
        b3 = *(const bf16x8*)&Bsm[P][3][n][kb1];             \
        acc[nf] = __builtin_amdgcn_mfma_f32_16x16x32_bf16(ax1, b0, acc[nf], 0, 0, 0); \
        acc[nf] = __builtin_amdgcn_mfma_f32_16x16x32_bf16(ax1, b1, acc[nf], 0, 0, 0); \
        acc[nf] = __builtin_amdgcn_mfma_f32_16x16x32_bf16(ah1, b2, acc[nf], 0, 0, 0); \
        acc[nf] = __builtin_amdgcn_mfma_f32_16x16x32_bf16(ah1, b3, acc[nf], 0, 0, 0); \
        acc[nf] = __builtin_amdgcn_mfma_f32_16x16x32_bf16(al1, b2, acc[nf], 0, 0, 0); \
    } }

    // prologue: depth-2 register staging of weights+noise
    STAGE(rwa, rza, 0);
    STAGE(rwb, rzb, KSTEP);

    for (int it = 0; it < NIT; it += 2) {
        // ---- iter it (buffer 0, staging set A) ----
        ALOAD(it * KSTEP);                         // short-latency, issued FIRST
        CVT(0, rwa, rza);                          // waits W(it), staged 2 iters ago
        if (it + 2 < NIT) STAGE(rwa, rza, (it + 2) * KSTEP);   // long-latency, issued LAST
        __syncthreads();
        COMPUTE(0);
        // ---- iter it+1 (buffer 1, staging set B) ----
        ALOAD((it + 1) * KSTEP);
        CVT(1, rwb, rzb);
        if (it + 3 < NIT) STAGE(rwb, rzb, (it + 3) * KSTEP);
        __syncthreads();
        COMPUTE(1);
    }

    // fused epilogue: nf == gate index (i,j,f,o); all gates in-lane
    int hcol = (cb << 4) + lh;
    float A3 = a3[nb], A4 = a4[nb], A5 = a5[nb], A6 = a6[nb], A7 = a7[nb];
    float A8 = a8[nb], A9 = a9[nb], A10 = a10[nb], A11 = a11[nb];
    float bc_i = bias_comb[nb * GDIM + hcol];
    float bc_j = bias_comb[nb * GDIM + 512 + hcol];
    float bc_f = bias_comb[nb * GDIM + 1024 + hcol];
    float bc_o = bias_comb[nb * GDIM + 1536 + hcol];
    #pragma unroll
    for (int rg = 0; rg < 4; ++rg) {
        int r = (wv << 4) + (g << 2) + rg;
        float gi = acc[0][rg] + bc_i;
        float gj = acc[1][rg] + bc_j;
        float gf = acc[2][rg] + bc_f;
        float go = acc[3][rg] + bc_o;
        float fg = qpact(sigmf(gf), A3);
        float ig = qpact(sigmf(gi), A4);
        float act = qpact(tanhf(gj), A5);
        float og = qpact(sigmf(go), A6);
        int oidx = (nb * BROWS + r) * HIDD + hcol;
        float cv = cx[oidx];
        float gated = qpact(cv * fg, A7);
        float actin = qpact(ig * act, A8);
        float ncv = qpact(gated + actin, A9);
        float acv = qpact(tanhf(ncv), A10);
        float nhv = qpact(acv * og, A11);
        out_h[oidx] = nhv;
        out_c[oidx] = ncv;
    }
}

extern "C" void kernel_launch(void* const* d_in, const int* in_sizes, int n_in,
                              void* d_out, int out_size, void* d_ws, size_t ws_size,
                              hipStream_t stream) {
    const float* input = (const float*)d_in[0];
    const float* hx    = (const float*)d_in[1];
    const float* cx    = (const float*)d_in[2];
    const float* w_ih  = (const float*)d_in[3];
    const float* w_hh  = (const float*)d_in[4];
    const float* b_ih  = (const float*)d_in[5];
    const float* b_hh  = (const float*)d_in[6];
    const float* n_wih = (const float*)d_in[7];
    const float* n_whh = (const float*)d_in[8];
    const float* n_bih = (const float*)d_in[9];
    const float* n_bhh = (const float*)d_in[10];
    const float* a1  = (const float*)d_in[11];
    const float* a3  = (const float*)d_in[12];
    const float* a4  = (const float*)d_in[13];
    const float* a5  = (const float*)d_in[14];
    const float* a6  = (const float*)d_in[15];
    const float* a7  = (const float*)d_in[16];
    const float* a8  = (const float*)d_in[17];
    const float* a9  = (const float*)d_in[18];
    const float* a10 = (const float*)d_in[19];
    const float* a11 = (const float*)d_in[20];

    float* out_h = (float*)d_out;
    float* out_c = out_h + NBATCH * BROWS * HIDD;

    char* ws = (char*)d_ws;
    unsigned* maxes = (unsigned*)ws;
    __hip_bfloat16* xqh = (__hip_bfloat16*)(ws + 256);
    __hip_bfloat16* hxh = (__hip_bfloat16*)(ws + 256 + 2097152);
    __hip_bfloat16* hxl = (__hip_bfloat16*)(ws + 256 + 2 * 2097152);
    float* bias_comb    = (float*)(ws + 256 + 3 * 2097152);

    hipMemsetAsync(maxes, 0, 32, stream);
    // 6 streams: w_ih, w_hh, b_ih, b_hh, n_wih, n_whh.  The noise streams warm
    // L3 so k_gemm's staging reads hit cache (the n maxes are simply unused).
    k_max<<<dim3(256, 6), 256, 0, stream>>>(w_ih, w_hh, b_ih, b_hh, n_wih, n_whh, maxes);
    k_prep<<<2048, 256, 0, stream>>>(input, hx, b_ih, b_hh, n_bih, n_bhh, a1, maxes,
                                     xqh, hxh, hxl, bias_comb);
    k_gemm<<<NBATCH * 32, 1024, 0, stream>>>(w_ih, w_hh, n_wih, n_whh, xqh, hxh, hxl,
                                             bias_comb, cx,
                                             a3, a4, a5, a6, a7, a8, a9, a10, a11,
                                             maxes, out_h, out_c);
}

// Round 8
// 83.287 us; speedup vs baseline: 1.7772x; 1.1416x over previous
//
#include <hip/hip_runtime.h>
#include <hip/hip_bf16.h>

#define NBATCH 8
#define BROWS 256
#define KDIM 512
#define HIDD 512
#define GDIM 2048
#define KSTEP 64
#define NIT (KDIM / KSTEP)

typedef float f32x4 __attribute__((ext_vector_type(4)));
typedef __bf16 bf16x8 __attribute__((ext_vector_type(8)));

__device__ __forceinline__ unsigned fenc(float f) {
    unsigned u = __float_as_uint(f);
    return (u & 0x80000000u) ? ~u : (u | 0x80000000u);
}
__device__ __forceinline__ float fdec(unsigned e) {
    unsigned u = (e & 0x80000000u) ? (e & 0x7fffffffu) : ~e;
    return __uint_as_float(u);
}
__device__ __forceinline__ unsigned umaxu(unsigned a, unsigned b) { return a > b ? a : b; }

// quant(pact(x,a), 8, a)  -- all a's are powers of 2 so /a, *a are exact
__device__ __forceinline__ float qpact(float x, float a) {
    float ax = fabsf(x);
    float p  = copysignf(0.5f * (ax - fabsf(ax - a) + a), x);
    float x01 = p / a;
    x01 = fminf(fmaxf(x01, -0.9921875f), 0.9921875f);
    return (rintf(x01 * 128.f) * 0.0078125f) * a;
}
// quant(x, 8, 1.0)
__device__ __forceinline__ float q1(float x) {
    float x01 = fminf(fmaxf(x, -0.9921875f), 0.9921875f);
    return rintf(x01 * 128.f) * 0.0078125f;
}
__device__ __forceinline__ float sigmf(float x) { return 1.0f / (1.0f + expf(-x)); }

__global__ void k_max(const float* __restrict__ w_ih, const float* __restrict__ w_hh,
                      const float* __restrict__ b_ih, const float* __restrict__ b_hh,
                      unsigned* __restrict__ omax) {
    int which = blockIdx.y;
    const float* src = which == 0 ? w_ih : which == 1 ? w_hh : which == 2 ? b_ih : b_hh;
    int n4 = (which < 2 ? NBATCH * KDIM * GDIM : NBATCH * GDIM) >> 2;
    unsigned best = 0u;
    int stride = gridDim.x * blockDim.x;
    for (int i = blockIdx.x * blockDim.x + threadIdx.x; i < n4; i += stride) {
        float4 v = ((const float4*)src)[i];
        best = umaxu(best, fenc(v.x)); best = umaxu(best, fenc(v.y));
        best = umaxu(best, fenc(v.z)); best = umaxu(best, fenc(v.w));
    }
    #pragma unroll
    for (int off = 32; off > 0; off >>= 1)
        best = umaxu(best, (unsigned)__shfl_down((int)best, off, 64));
    __shared__ unsigned red[4];
    int lane = threadIdx.x & 63, wv = threadIdx.x >> 6;
    if (lane == 0) red[wv] = best;
    __syncthreads();
    if (threadIdx.x == 0) {
        unsigned b2 = umaxu(umaxu(red[0], red[1]), umaxu(red[2], red[3]));
        atomicMax(&omax[which], b2);
    }
}

__global__ void k_prep(const float* __restrict__ input, const float* __restrict__ hx,
                       const float* __restrict__ bih, const float* __restrict__ bhh,
                       const float* __restrict__ nbih, const float* __restrict__ nbhh,
                       const float* __restrict__ a1, const unsigned* __restrict__ maxes,
                       __hip_bfloat16* __restrict__ xqh, __hip_bfloat16* __restrict__ hxh,
                       __hip_bfloat16* __restrict__ hxl, float* __restrict__ bias_comb) {
    const int NX = NBATCH * BROWS * KDIM;
    const int NH = NBATCH * BROWS * HIDD;
    const int NBC = NBATCH * GDIM;
    int total = NX + NH + NBC;
    int stride = gridDim.x * blockDim.x;
    for (int i = blockIdx.x * blockDim.x + threadIdx.x; i < total; i += stride) {
        if (i < NX) {
            int nb = i >> 17;              // /(256*512)
            int rem = i & 131071;
            float v = qpact(input[rem], a1[nb]);
            xqh[i] = __float2bfloat16(v);  // exact: integers <=127 for a1=128
        } else if (i < NX + NH) {
            int j = i - NX;
            float h = hx[j];
            __hip_bfloat16 hi = __float2bfloat16(h);
            hxh[j] = hi;
            hxl[j] = __float2bfloat16(h - __bfloat162float(hi));
        } else {
            int j = i - NX - NH;
            float mb_ih = fdec(maxes[2]);
            float mb_hh = fdec(maxes[3]);
            bias_comb[j] = q1(bih[j]) + (nbih[j] * mb_ih) * 0.05f
                         + q1(bhh[j]) + (nbhh[j] * mb_hh) * 0.05f;
        }
    }
}

// block owns 64 CONTIGUOUS G-cols (gc) -> all weight/noise staging reads are
// 256B-contiguous per wave-instruction (the cold z-stream becomes DRAM-efficient).
// Gates (+bias) are written raw to ws; k_cell applies the LSTM chain.
__global__ __launch_bounds__(1024, 1) void k_gemm(
    const float* __restrict__ w_ih, const float* __restrict__ w_hh,
    const float* __restrict__ n_ih, const float* __restrict__ n_hh,
    const __hip_bfloat16* __restrict__ xqh, const __hip_bfloat16* __restrict__ hxh,
    const __hip_bfloat16* __restrict__ hxl,
    const float* __restrict__ bias_comb,
    const unsigned* __restrict__ maxes,
    float* __restrict__ gates)
{
    // double-buffered B tiles: [buf][mat][n=64][k=64 pad 72] bf16 -> 72 KB
    __shared__ __hip_bfloat16 Bsm[2][4][64][72];

    int tid = threadIdx.x;
    int lane = tid & 63, wv = tid >> 6;          // 16 waves
    int nb = blockIdx.x & 7;                     // batch -> XCD round-robin
    int gc = blockIdx.x >> 3;                    // 32 blocks of 64 contiguous G-cols

    const float* wih_b = w_ih + nb * KDIM * GDIM;
    const float* whh_b = w_hh + nb * KDIM * GDIM;
    const float* nih_b = n_ih + nb * KDIM * GDIM;
    const float* nhh_b = n_hh + nb * KDIM * GDIM;
    const __hip_bfloat16* xq_b = xqh + nb * BROWS * KDIM;
    const __hip_bfloat16* hh_b = hxh + nb * BROWS * KDIM;
    const __hip_bfloat16* hl_b = hxl + nb * BROWS * KDIM;

    float c_ih = fdec(maxes[0]);
    float c_hh = fdec(maxes[1]);

    f32x4 acc[4] = {};                           // one 16-row m-frag x 4 col-frags

    int lh = lane & 15;
    int g  = lane >> 4;                          // 0..3
    int arow = (wv << 4) + lh;                   // this wave's 16 rows

    // staging map: thread -> one col n (0..63), one k-octet, one matrix pair
    int sn   = tid & 63;
    int soct = (tid >> 6) & 7;
    int shh  = tid >> 9;                         // 0: ih pair, 1: hh pair (wave-uniform)
    const float* wsrc = shh ? whh_b : wih_b;
    const float* zsrc = shh ? nhh_b : nih_b;
    float cmax = shh ? c_hh : c_ih;
    int matHi = shh << 1;                        // 0 or 2
    int scol = (gc << 6) + sn;                   // CONTIGUOUS across the wave

    float rwa[8], rza[8], rwb[8], rzb[8];
    bf16x8 ax0, ax1, ah0, ah1, al0, al1;

#define STAGE(RW, RZ, K0) {                                  \
    int kb = (K0) + (soct << 3);                             \
    _Pragma("unroll")                                        \
    for (int j = 0; j < 8; ++j) {                            \
        int gx = (kb + j) * GDIM + scol;                     \
        RW[j] = wsrc[gx]; RZ[j] = zsrc[gx];                  \
    } }

#define ALOAD(K0) {                                          \
    int a0 = arow * KDIM + (K0) + (g << 3);                  \
    ax0 = *(const bf16x8*)(xq_b + a0);                       \
    ax1 = *(const bf16x8*)(xq_b + a0 + 32);                  \
    ah0 = *(const bf16x8*)(hh_b + a0);                       \
    ah1 = *(const bf16x8*)(hh_b + a0 + 32);                  \
    al0 = *(const bf16x8*)(hl_b + a0);                       \
    al1 = *(const bf16x8*)(hl_b + a0 + 32);                  \
    }

#define CVT(P, RW, RZ) {                                     \
    bf16x8 hi8, lo8;                                         \
    _Pragma("unroll")                                        \
    for (int j = 0; j < 8; ++j) {                            \
        float w = RW[j];                                     \
        float wq = rintf(fminf(fmaxf(w, -0.9921875f), 0.9921875f) * 128.f) * 0.0078125f; \
        float e = wq + (RZ[j] * cmax) * 0.05f;               \
        __hip_bfloat16 h = __float2bfloat16(e);              \
        float lo = e - __bfloat162float(h);                  \
        __hip_bfloat16 l = __float2bfloat16(lo);             \
        hi8[j] = *reinterpret_cast<__bf16*>(&h);             \
        lo8[j] = *reinterpret_cast<__bf16*>(&l);             \
    }                                                        \
    *(bf16x8*)&Bsm[P][matHi][sn][soct << 3] = hi8;           \
    *(bf16x8*)&Bsm[P][matHi + 1][sn][soct << 3] = lo8; }

#define COMPUTE(P) {                                         \
    _Pragma("unroll")                                        \
    for (int nf = 0; nf < 4; ++nf) {                         \
        int n = (nf << 4) + lh;                              \
        int kb0 = g << 3, kb1 = 32 + kb0;                    \
        bf16x8 b0 = *(const bf16x8*)&Bsm[P][0][n][kb0];      \
        bf16x8 b1 = *(const bf16x8*)&Bsm[P][1][n][kb0];      \
        bf16x8 b2 = *(const bf16x8*)&Bsm[P][2][n][kb0];      \
        bf16x8 b3 = *(const bf16x8*)&Bsm[P][3][n][kb0];      \
        acc[nf] = __builtin_amdgcn_mfma_f32_16x16x32_bf16(ax0, b0, acc[nf], 0, 0, 0); \
        acc[nf] = __builtin_amdgcn_mfma_f32_16x16x32_bf16(ax0, b1, acc[nf], 0, 0, 0); \
        acc[nf] = __builtin_amdgcn_mfma_f32_16x16x32_bf16(ah0, b2, acc[nf], 0, 0, 0); \
        acc[nf] = __builtin_amdgcn_mfma_f32_16x16x32_bf16(ah0, b3, acc[nf], 0, 0, 0); \
        acc[nf] = __builtin_amdgcn_mfma_f32_16x16x32_bf16(al0, b2, acc[nf], 0, 0, 0); \
        b0 = *(const bf16x8*)&Bsm[P][0][n][kb1];             \
        b1 = *(const bf16x8*)&Bsm[P][1][n][kb1];             \
        b2 = *(const bf16x8*)&Bsm[P][2][n][kb1];             \
        b3 = *(const bf16x8*)&Bsm[P][3][n][kb1];             \
        acc[nf] = __builtin_amdgcn_mfma_f32_16x16x32_bf16(ax1, b0, acc[nf], 0, 0, 0); \
        acc[nf] = __builtin_amdgcn_mfma_f32_16x16x32_bf16(ax1, b1, acc[nf], 0, 0, 0); \
        acc[nf] = __builtin_amdgcn_mfma_f32_16x16x32_bf16(ah1, b2, acc[nf], 0, 0, 0); \
        acc[nf] = __builtin_amdgcn_mfma_f32_16x16x32_bf16(ah1, b3, acc[nf], 0, 0, 0); \
        acc[nf] = __builtin_amdgcn_mfma_f32_16x16x32_bf16(al1, b2, acc[nf], 0, 0, 0); \
    } }

    // prologue: depth-2 register staging of weights+noise
    STAGE(rwa, rza, 0);
    STAGE(rwb, rzb, KSTEP);

    for (int it = 0; it < NIT; it += 2) {
        // ---- iter it (buffer 0, staging set A) ----
        ALOAD(it * KSTEP);                         // short-latency, issued FIRST
        CVT(0, rwa, rza);                          // waits W(it), staged 2 iters ago
        if (it + 2 < NIT) STAGE(rwa, rza, (it + 2) * KSTEP);   // long-latency, issued LAST
        __syncthreads();
        COMPUTE(0);
        // ---- iter it+1 (buffer 1, staging set B) ----
        ALOAD((it + 1) * KSTEP);
        CVT(1, rwb, rzb);
        if (it + 3 < NIT) STAGE(rwb, rzb, (it + 3) * KSTEP);
        __syncthreads();
        COMPUTE(1);
    }

    // epilogue: write raw gates (+combined bias), coalesced fp32
    #pragma unroll
    for (int nf = 0; nf < 4; ++nf) {
        int gcol = (gc << 6) + (nf << 4) + lh;
        float bc = bias_comb[nb * GDIM + gcol];
        #pragma unroll
        for (int rg = 0; rg < 4; ++rg) {
            int r = (wv << 4) + (g << 2) + rg;
            gates[((nb * BROWS + r) * GDIM) + gcol] = acc[nf][rg] + bc;
        }
    }
}

// elementwise LSTM chain: one float4 (4 hcols) per thread
__global__ __launch_bounds__(512) void k_cell(
    const float* __restrict__ gates, const float* __restrict__ cx,
    const float* __restrict__ a3, const float* __restrict__ a4, const float* __restrict__ a5,
    const float* __restrict__ a6, const float* __restrict__ a7, const float* __restrict__ a8,
    const float* __restrict__ a9, const float* __restrict__ a10, const float* __restrict__ a11,
    float* __restrict__ out_h, float* __restrict__ out_c)
{
    int idx = blockIdx.x * blockDim.x + threadIdx.x;   // 0..262143
    int nb = idx >> 15;                                // 32768 quads per batch
    int rem = idx & 32767;
    const float* gb = gates + (size_t)(nb * BROWS * GDIM) + rem * 4
                    - (rem >> 7) * 2048 + (rem >> 7) * 2048;  // simplify below
    int row = rem >> 7;            // 128 quads per 512-col row
    int hq  = rem & 127;
    const float* gr = gates + ((size_t)(nb * BROWS + row) * GDIM) + hq * 4;
    f32x4 gi = *(const f32x4*)(gr);
    f32x4 gj = *(const f32x4*)(gr + 512);
    f32x4 gf = *(const f32x4*)(gr + 1024);
    f32x4 go = *(const f32x4*)(gr + 1536);
    int oidx = (nb * BROWS + row) * HIDD + hq * 4;
    f32x4 cv = *(const f32x4*)(cx + oidx);
    float A3 = a3[nb], A4 = a4[nb], A5 = a5[nb], A6 = a6[nb], A7 = a7[nb];
    float A8 = a8[nb], A9 = a9[nb], A10 = a10[nb], A11 = a11[nb];
    f32x4 nh, nc;
    #pragma unroll
    for (int j = 0; j < 4; ++j) {
        float fg = qpact(sigmf(gf[j]), A3);
        float ig = qpact(sigmf(gi[j]), A4);
        float act = qpact(tanhf(gj[j]), A5);
        float og = qpact(sigmf(go[j]), A6);
        float gated = qpact(cv[j] * fg, A7);
        float actin = qpact(ig * act, A8);
        float ncv = qpact(gated + actin, A9);
        float acv = qpact(tanhf(ncv), A10);
        nh[j] = qpact(acv * og, A11);
        nc[j] = ncv;
    }
    *(f32x4*)(out_h + oidx) = nh;
    *(f32x4*)(out_c + oidx) = nc;
}

extern "C" void kernel_launch(void* const* d_in, const int* in_sizes, int n_in,
                              void* d_out, int out_size, void* d_ws, size_t ws_size,
                              hipStream_t stream) {
    const float* input = (const float*)d_in[0];
    const float* hx    = (const float*)d_in[1];
    const float* cx    = (const float*)d_in[2];
    const float* w_ih  = (const float*)d_in[3];
    const float* w_hh  = (const float*)d_in[4];
    const float* b_ih  = (const float*)d_in[5];
    const float* b_hh  = (const float*)d_in[6];
    const float* n_wih = (const float*)d_in[7];
    const float* n_whh = (const float*)d_in[8];
    const float* n_bih = (const float*)d_in[9];
    const float* n_bhh = (const float*)d_in[10];
    const float* a1  = (const float*)d_in[11];
    const float* a3  = (const float*)d_in[12];
    const float* a4  = (const float*)d_in[13];
    const float* a5  = (const float*)d_in[14];
    const float* a6  = (const float*)d_in[15];
    const float* a7  = (const float*)d_in[16];
    const float* a8  = (const float*)d_in[17];
    const float* a9  = (const float*)d_in[18];
    const float* a10 = (const float*)d_in[19];
    const float* a11 = (const float*)d_in[20];

    float* out_h = (float*)d_out;
    float* out_c = out_h + NBATCH * BROWS * HIDD;

    char* ws = (char*)d_ws;
    unsigned* maxes = (unsigned*)ws;
    __hip_bfloat16* xqh = (__hip_bfloat16*)(ws + 256);
    __hip_bfloat16* hxh = (__hip_bfloat16*)(ws + 256 + 2097152);
    __hip_bfloat16* hxl = (__hip_bfloat16*)(ws + 256 + 2 * 2097152);
    float* bias_comb    = (float*)(ws + 256 + 3 * 2097152);
    float* gates        = (float*)(ws + 256 + 3 * 2097152 + 65536);

    hipMemsetAsync(maxes, 0, 32, stream);
    k_max<<<dim3(256, 4), 256, 0, stream>>>(w_ih, w_hh, b_ih, b_hh, maxes);
    k_prep<<<2048, 256, 0, stream>>>(input, hx, b_ih, b_hh, n_bih, n_bhh, a1, maxes,
                                     xqh, hxh, hxl, bias_comb);
    k_gemm<<<NBATCH * 32, 1024, 0, stream>>>(w_ih, w_hh, n_wih, n_whh, xqh, hxh, hxl,
                                             bias_comb, maxes, gates);
    k_cell<<<512, 512, 0, stream>>>(gates, cx, a3, a4, a5, a6, a7, a8, a9, a10, a11,
                                    out_h, out_c);
}